// Round 2
// baseline (1891.282 us; speedup 1.0000x reference)
//
#include <hip/hip_runtime.h>
#include <hip/hip_bf16.h>
#include <stdint.h>

// Problem constants
#define TOK 8192   // B*S
#define HD  1024   // H
#define FD  4096   // F
#define NE  8      // experts

// Workspace layout (bytes). Total ~278 MB.
#define WS_CNT 0
#define WS_RW  1024
#define WS_LST 131072
#define WS_PRB 524288
#define WS_PART 786432
#define WS_XB  ((size_t)1  << 20)   // xb: 8192*1024*2   = 16 MiB
#define WS_W1T ((size_t)18 << 20)   // W1T: 8*4096*1024*2 = 64 MiB
#define WS_W2T ((size_t)84 << 20)   // W2T: 8*1024*4096*2 = 64 MiB
#define WS_H   ((size_t)150 << 20)  // hbuf: 16384*4096*2 = 128 MiB
#define WS_Y   WS_W1T               // ybuf overlays W1T (dead after gemm1)

typedef __attribute__((ext_vector_type(4))) float  f32x4;
typedef __attribute__((ext_vector_type(8))) short  s16x8;
typedef __attribute__((ext_vector_type(4))) short  s16x4;
typedef __attribute__((ext_vector_type(8))) __bf16 bf16x8;

__device__ inline unsigned short f2bf(float f) {
    __hip_bfloat16 h = __float2bfloat16(f);   // RNE
    return __builtin_bit_cast(unsigned short, h);
}
__device__ inline float bf2f(unsigned short s) {
    unsigned u = ((unsigned)s) << 16;
    return __builtin_bit_cast(float, u);
}
__device__ inline f32x4 mfma_bf16(s16x8 a, s16x8 b, f32x4 c) {
    return __builtin_amdgcn_mfma_f32_16x16x32_bf16(
        __builtin_bit_cast(bf16x8, a), __builtin_bit_cast(bf16x8, b), c, 0, 0, 0);
}
// async global->LDS, 16B per lane. LDS dest wave-uniform base (+lane*16 implicit).
__device__ inline void gl2lds16(const void* g, void* l) {
    __builtin_amdgcn_global_load_lds(
        (const __attribute__((address_space(1))) unsigned int*)g,
        (__attribute__((address_space(3))) unsigned int*)l, 16, 0, 0);
}

// ---------------- Prep: x fp32 -> bf16 ----------------
__global__ __launch_bounds__(256) void cvt_x_kernel(
    const float* __restrict__ x, unsigned short* __restrict__ xb)
{
    size_t g = ((size_t)blockIdx.x * 256 + threadIdx.x) * 8;
    f32x4 a = *(const f32x4*)&x[g];
    f32x4 b = *(const f32x4*)&x[g + 4];
    s16x8 v;
    v[0]=(short)f2bf(a[0]); v[1]=(short)f2bf(a[1]); v[2]=(short)f2bf(a[2]); v[3]=(short)f2bf(a[3]);
    v[4]=(short)f2bf(b[0]); v[5]=(short)f2bf(b[1]); v[6]=(short)f2bf(b[2]); v[7]=(short)f2bf(b[3]);
    *(s16x8*)&xb[g] = v;
}

// ---------------- Prep: transpose + cvt.  src [P][R][C] fp32 -> dst [P][C][R] bf16
__global__ __launch_bounds__(256) void transpose_cvt_kernel(
    const float* __restrict__ src, unsigned short* __restrict__ dst, int R, int C)
{
    __shared__ unsigned short tile[64][65];
    int p  = blockIdx.z;
    int r0 = blockIdx.y * 64, c0 = blockIdx.x * 64;
    const float* s = src + ((size_t)p * R + r0) * C + c0;
    int tc = threadIdx.x & 63, tr = threadIdx.x >> 6;
    #pragma unroll
    for (int i = 0; i < 16; ++i) {
        int r = i * 4 + tr;
        tile[r][tc] = f2bf(s[(size_t)r * C + tc]);
    }
    __syncthreads();
    unsigned short* d = dst + ((size_t)p * C + c0) * R + r0;
    int hq = (threadIdx.x & 15) * 4;
    int fb = threadIdx.x >> 4;
    #pragma unroll
    for (int i = 0; i < 4; ++i) {
        int c = i * 16 + fb;
        s16x4 v;
        v[0] = (short)tile[hq + 0][c]; v[1] = (short)tile[hq + 1][c];
        v[2] = (short)tile[hq + 2][c]; v[3] = (short)tile[hq + 3][c];
        *(s16x4*)&d[(size_t)c * R + hq] = v;
    }
}

// ---------------- Router: 1 wave per token ----------------
__global__ __launch_bounds__(256) void router_kernel(
    const float* __restrict__ x, const float* __restrict__ Wr,
    const float* __restrict__ br, int* __restrict__ cnt,
    int* __restrict__ lists, float* __restrict__ rw,
    float* __restrict__ probs)
{
    int gid  = blockIdx.x * 256 + threadIdx.x;
    int tok  = gid >> 6;
    int lane = threadIdx.x & 63;
    const float* xr = x + (size_t)tok * HD;
    float acc[NE] = {0.f,0.f,0.f,0.f,0.f,0.f,0.f,0.f};
    #pragma unroll 4
    for (int i = 0; i < HD / 64; ++i) {
        float xv = xr[i * 64 + lane];
        const f32x4* w = (const f32x4*)(Wr + (size_t)(i * 64 + lane) * NE);
        f32x4 w0 = w[0], w1 = w[1];
        acc[0] += xv * w0[0]; acc[1] += xv * w0[1];
        acc[2] += xv * w0[2]; acc[3] += xv * w0[3];
        acc[4] += xv * w1[0]; acc[5] += xv * w1[1];
        acc[6] += xv * w1[2]; acc[7] += xv * w1[3];
    }
    #pragma unroll
    for (int e = 0; e < NE; ++e) {
        float v = acc[e];
        #pragma unroll
        for (int off = 32; off > 0; off >>= 1) v += __shfl_down(v, off);
        acc[e] = v;
    }
    if (lane == 0) {
        float lg[NE];
        #pragma unroll
        for (int e = 0; e < NE; ++e) lg[e] = acc[e] + br[e];
        float m = lg[0];
        #pragma unroll
        for (int e = 1; e < NE; ++e) m = fmaxf(m, lg[e]);
        float s = 0.f, p[NE];
        #pragma unroll
        for (int e = 0; e < NE; ++e) { p[e] = __expf(lg[e] - m); s += p[e]; }
        float inv = 1.f / s;
        f32x4 p0 = {p[0]*inv, p[1]*inv, p[2]*inv, p[3]*inv};
        f32x4 p1 = {p[4]*inv, p[5]*inv, p[6]*inv, p[7]*inv};
        *(f32x4*)&probs[(size_t)tok * NE]     = p0;
        *(f32x4*)&probs[(size_t)tok * NE + 4] = p1;
        int e0 = 0;
        #pragma unroll
        for (int e = 1; e < NE; ++e) if (lg[e] > lg[e0]) e0 = e;
        int e1 = (e0 == 0) ? 1 : 0;
        #pragma unroll
        for (int e = 0; e < NE; ++e) if (e != e0 && lg[e] > lg[e1]) e1 = e;
        float t1 = __expf(lg[e1] - lg[e0]);
        float w0 = 1.f / (1.f + t1);
        rw[tok * 2 + 0] = w0;
        rw[tok * 2 + 1] = t1 * w0;
        int p0i = atomicAdd(&cnt[e0], 1);
        lists[e0 * TOK + p0i] = (tok << 1);
        int p1i = atomicAdd(&cnt[e1], 1);
        lists[e1 * TOK + p1i] = (tok << 1) | 1;
    }
}

// ============ GEMM machinery: 256x256 tile, BK=64, 8 waves, 8-phase schedule ============
// LDS: 2 K-tile buffers, each A[256][64] + B[256][64] bf16 (32 KiB each) = 128 KiB total.
// Row chunking: 8 chunks of 8 elems (16 B); chunk slot c' = c ^ (row & 7) (3-bit XOR swizzle).
// Staging: global_load_lds writes linearly; source address pre-swizzled (Guideline 21).
//
// Phase plan per K-tile T (quadrants (mh,kk)), buffer c = T&1:
//   p0 (mh0,k0): read A+Bk0 frags, stage A-half0[T+1] -> buf c^1
//   p1 (mh0,k1): read A+Bk1 frags, stage A-half1[T+1] -> buf c^1
//   p2 (mh1,k0): read A frags (B from regs), stage B-half0[T+2] -> buf c (B region dead after p1)
//   p3 (mh1,k1): read A frags,               stage B-half1[T+2] -> buf c, then vmcnt(4)
// Each phase: {ds_reads; stage; [wait]; barrier; lgkmcnt(0); setprio(1); 16 MFMA; setprio(0); barrier}.
//
// RACE DISCIPLINE (round-1 post-mortem): vmcnt is PER-WAVE. A buffer is readable only after
// {each wave waits on its OWN loads for it} -> {barrier} -> {reads}. So the counted wait for
// tile T+1's buffer sits at T's p3 BEFORE p3's barriers; T+1 p0's ds_reads follow those
// barriers. At p3 (after STAGE_B(T+2,1)) per-wave outstanding = B[T+1](4) + A[T+1](4) +
// B[T+2](4) = 12; vmcnt(4) drains the 8 oldest = exactly A[T+1]+B[T+1], leaving B[T+2] in
// flight (never drains to 0 in steady state). Prologue: vmcnt(4)+barrier before first read.
// Tail: at T = NT-2 only A[NT-1] is in flight at p3 -> vmcnt(0); last tile: no wait.

#define STAGE_A(kt3, h)                                                           \
    { int b_s = (kt3) & 1;                                                        \
      gl2lds16(ga[h][0] + (size_t)(kt3) * 64, &As[b_s][((h) * 128 + w * 16 + 0) * 64]); \
      gl2lds16(ga[h][1] + (size_t)(kt3) * 64, &As[b_s][((h) * 128 + w * 16 + 8) * 64]); }

#define STAGE_B(kt3, h)                                                           \
    { int b_s = (kt3) & 1;                                                        \
      gl2lds16(gb[h][0] + (size_t)(kt3) * 64, &Bs[b_s][((h) * 128 + w * 16 + 0) * 64]); \
      gl2lds16(gb[h][1] + (size_t)(kt3) * 64, &Bs[b_s][((h) * 128 + w * 16 + 8) * 64]); }

#define VM4 asm volatile("s_waitcnt vmcnt(4)" ::: "memory")
#define VM0 asm volatile("s_waitcnt vmcnt(0)" ::: "memory")
#define NOPS (void)0

#define PHASE(kt, mh, kk, READ_B, STAGE_STMT, WAIT_STMT)                          \
    {                                                                             \
        int b_ = (kt) & 1;                                                        \
        s16x8 af[4];                                                              \
        _Pragma("unroll")                                                         \
        for (int mi = 0; mi < 4; ++mi) {                                          \
            int r = wr * 128 + (mh) * 64 + mi * 16 + rl;                          \
            af[mi] = *(const s16x8*)&As[b_][r * 64 + ((((kk) * 4 + q) ^ (r & 7)) << 3)]; \
        }                                                                         \
        if (READ_B) {                                                             \
            _Pragma("unroll")                                                     \
            for (int ni = 0; ni < 4; ++ni) {                                      \
                int n = wcn * 64 + ni * 16 + rl;                                  \
                bf[(kk) * 4 + ni] = *(const s16x8*)&Bs[b_][n * 64 + ((((kk) * 4 + q) ^ (n & 7)) << 3)]; \
            }                                                                     \
        }                                                                         \
        STAGE_STMT;                                                               \
        WAIT_STMT;                                                                \
        __builtin_amdgcn_s_barrier();                                             \
        asm volatile("s_waitcnt lgkmcnt(0)" ::: "memory");                        \
        __builtin_amdgcn_s_setprio(1);                                            \
        _Pragma("unroll")                                                         \
        for (int mi = 0; mi < 4; ++mi)                                            \
            _Pragma("unroll")                                                     \
            for (int ni = 0; ni < 4; ++ni)                                        \
                acc[(mh) * 4 + mi][ni] = mfma_bf16(af[mi], bf[(kk) * 4 + ni], acc[(mh) * 4 + mi][ni]); \
        __builtin_amdgcn_s_setprio(0);                                            \
        __builtin_amdgcn_s_barrier();                                             \
    }

// Prologue issue order (vmcnt counting depends on it): B[0]h0, B[0]h1, A[0]h0, A[0]h1,
// B[1]h0, B[1]h1 (12 loads/wave), then vmcnt(4) (drains A[0]+B[0]) + barrier.
#define GEMM8_MAIN(NT)                                                            \
    STAGE_B(0, 0); STAGE_B(0, 1); STAGE_A(0, 0); STAGE_A(0, 1);                   \
    STAGE_B(1, 0); STAGE_B(1, 1);                                                 \
    VM4;                                                                          \
    __builtin_amdgcn_s_barrier();                                                 \
    f32x4 acc[8][4];                                                              \
    _Pragma("unroll")                                                             \
    for (int i_ = 0; i_ < 8; ++i_)                                                \
        _Pragma("unroll")                                                         \
        for (int j_ = 0; j_ < 4; ++j_) acc[i_][j_] = (f32x4){0.f, 0.f, 0.f, 0.f}; \
    s16x8 bf[8];                                                                  \
    for (int kt = 0; kt < (NT); ++kt) {                                           \
        PHASE(kt, 0, 0, 1, if (kt + 1 < (NT)) STAGE_A(kt + 1, 0), NOPS)           \
        PHASE(kt, 0, 1, 1, if (kt + 1 < (NT)) STAGE_A(kt + 1, 1), NOPS)           \
        PHASE(kt, 1, 0, 0, if (kt + 2 < (NT)) STAGE_B(kt + 2, 0), NOPS)           \
        PHASE(kt, 1, 1, 0, if (kt + 2 < (NT)) STAGE_B(kt + 2, 1),                 \
              if (kt + 2 < (NT)) { VM4; } else if (kt + 1 < (NT)) { VM0; })       \
    }

// ---------------- GEMM1: hbuf[base+row] = gelu(xb[tok(row)] @ W1T[e]^T + b1[e]) ----------------
__global__ __launch_bounds__(512, 2) void gemm1_kernel(
    const unsigned short* __restrict__ xb, const unsigned short* __restrict__ w1t,
    const float* __restrict__ b1, const int* __restrict__ cnt,
    const int* __restrict__ lists, unsigned short* __restrict__ hbuf)
{
    // T1: XCD-aware swizzle with by' == xcd (mod 8) so active row-blocks spread over all XCDs
    int id = blockIdx.y * 16 + blockIdx.x;   // nwg = 512 per expert (mult of 8)
    int s_ = id >> 3;
    int by = (id & 7) + ((s_ & 3) << 3);     // 0..31
    int bx = s_ >> 2;                        // 0..15
    int e = blockIdx.z;
    int nc = cnt[e];
    int row0 = by * 256;
    if (row0 >= nc) return;
    int base = 0;
    for (int i = 0; i < e; ++i) base += cnt[i];
    int cb = bx * 256;

    __shared__ unsigned short As[2][256 * 64];
    __shared__ unsigned short Bs[2][256 * 64];

    int tid  = threadIdx.x;
    int lane = tid & 63;
    int w    = tid >> 6;     // 0..7
    int wr   = w >> 2;       // M half (0..1)
    int wcn  = w & 3;        // N quarter (0..3)
    int rl   = lane & 15;
    int q    = lane >> 4;    // k-chunk-within-32 (0..3)
    int ls   = lane >> 3;    // 0..7 sub-row within 8-row stage group
    int kc8  = ((lane & 7) ^ ls) << 3;   // pre-swizzled source chunk offset (elems)

    const unsigned short* ga[2][2];
    const unsigned short* gb[2][2];
    #pragma unroll
    for (int h = 0; h < 2; ++h)
        #pragma unroll
        for (int i = 0; i < 2; ++i) {
            int rit = h * 128 + w * 16 + i * 8 + ls;      // row in tile 0..255
            int lr  = row0 + rit;
            int tok = (lr < nc) ? (lists[e * TOK + lr] >> 1) : 0;
            ga[h][i] = xb + (size_t)tok * HD + kc8;
            gb[h][i] = w1t + ((size_t)e * FD + cb + rit) * HD + kc8;
        }

    GEMM8_MAIN(HD / 64)   // 16 K-tiles

    // epilogue: + b1, exact GELU, bf16 store, expert-packed rows
    int col0 = cb + wcn * 64 + rl;
    float b1v[4];
    #pragma unroll
    for (int ni = 0; ni < 4; ++ni) b1v[ni] = b1[e * FD + col0 + ni * 16];
    #pragma unroll
    for (int a = 0; a < 8; ++a) {
        #pragma unroll
        for (int j = 0; j < 4; ++j) {
            int grow = row0 + wr * 128 + (a >> 2) * 64 + (a & 3) * 16 + q * 4 + j;
            if (grow < nc) {
                unsigned short* dst = hbuf + (size_t)(base + grow) * FD + col0;
                #pragma unroll
                for (int ni = 0; ni < 4; ++ni) {
                    float v = acc[a][ni][j] + b1v[ni];
                    v = 0.5f * v * (1.f + erff(v * 0.70710678118654752f));
                    dst[ni * 16] = f2bf(v);
                }
            }
        }
    }
}

// ---------------- GEMM2: y = hbuf[base+row] @ W2T[e]^T + b2[e], scatter to ybuf ----------------
__global__ __launch_bounds__(512, 2) void gemm2_kernel(
    const unsigned short* __restrict__ hbuf, const unsigned short* __restrict__ w2t,
    const float* __restrict__ b2, const int* __restrict__ cnt,
    const int* __restrict__ lists, unsigned short* __restrict__ ybuf)
{
    int id = blockIdx.y * 4 + blockIdx.x;    // nwg = 128 per expert (mult of 8)
    int s_ = id >> 3;
    int by = (id & 7) + ((s_ & 3) << 3);     // 0..31
    int bx = s_ >> 2;                        // 0..3
    int e = blockIdx.z;
    int nc = cnt[e];
    int row0 = by * 256;
    if (row0 >= nc) return;
    int base = 0;
    for (int i = 0; i < e; ++i) base += cnt[i];
    int cb = bx * 256;

    __shared__ unsigned short As[2][256 * 64];
    __shared__ unsigned short Bs[2][256 * 64];

    int tid  = threadIdx.x;
    int lane = tid & 63;
    int w    = tid >> 6;
    int wr   = w >> 2;
    int wcn  = w & 3;
    int rl   = lane & 15;
    int q    = lane >> 4;
    int ls   = lane >> 3;
    int kc8  = ((lane & 7) ^ ls) << 3;

    const unsigned short* ga[2][2];
    const unsigned short* gb[2][2];
    #pragma unroll
    for (int h = 0; h < 2; ++h)
        #pragma unroll
        for (int i = 0; i < 2; ++i) {
            int rit = h * 128 + w * 16 + i * 8 + ls;
            int lr  = row0 + rit;
            int hrow = base + ((lr < nc) ? lr : (nc - 1));
            ga[h][i] = hbuf + (size_t)hrow * FD + kc8;
            gb[h][i] = w2t + ((size_t)e * HD + cb + rit) * FD + kc8;
        }

    GEMM8_MAIN(FD / 64)   // 64 K-tiles

    int col0 = cb + wcn * 64 + rl;
    float b2v[4];
    #pragma unroll
    for (int ni = 0; ni < 4; ++ni) b2v[ni] = b2[e * HD + col0 + ni * 16];
    #pragma unroll
    for (int a = 0; a < 8; ++a) {
        #pragma unroll
        for (int j = 0; j < 4; ++j) {
            int grow = row0 + wr * 128 + (a >> 2) * 64 + (a & 3) * 16 + q * 4 + j;
            if (grow < nc) {
                int entry = lists[e * TOK + grow];
                unsigned short* dst = ybuf + ((size_t)((entry & 1) * TOK + (entry >> 1))) * HD + col0;
                #pragma unroll
                for (int ni = 0; ni < 4; ++ni)
                    dst[ni * 16] = f2bf(acc[a][ni][j] + b2v[ni]);
            }
        }
    }
}

// ---------------- Gather: out = w0*y[k=0] + w1*y[k=1] ----------------
__global__ __launch_bounds__(256) void gather_kernel(
    const unsigned short* __restrict__ ybuf, const float* __restrict__ rw,
    float* __restrict__ out)
{
    int g = blockIdx.x * 256 + threadIdx.x;
    int t = g >> 7;
    int h0 = (g & 127) * 8;
    float w0 = rw[t * 2 + 0];
    float w1 = rw[t * 2 + 1];
    s16x8 y0 = *(const s16x8*)&ybuf[(size_t)t * HD + h0];
    s16x8 y1 = *(const s16x8*)&ybuf[((size_t)TOK + t) * HD + h0];
    f32x4 o0, o1;
    #pragma unroll
    for (int j = 0; j < 4; ++j) {
        o0[j] = w0 * bf2f((unsigned short)y0[j])   + w1 * bf2f((unsigned short)y1[j]);
        o1[j] = w0 * bf2f((unsigned short)y0[j+4]) + w1 * bf2f((unsigned short)y1[j+4]);
    }
    *(f32x4*)&out[(size_t)t * HD + h0]     = o0;
    *(f32x4*)&out[(size_t)t * HD + h0 + 4] = o1;
}

// ---------------- Aux loss: 32-block partial + final reduce ----------------
__global__ __launch_bounds__(256) void aux1_kernel(
    const float* __restrict__ probs, float* __restrict__ partial)
{
    __shared__ float sm[256 * NE];
    int tid = threadIdx.x;
    int t = blockIdx.x * 256 + tid;
    const f32x4* p = (const f32x4*)&probs[(size_t)t * NE];
    f32x4 a = p[0], b = p[1];
    sm[tid*NE+0]=a[0]; sm[tid*NE+1]=a[1]; sm[tid*NE+2]=a[2]; sm[tid*NE+3]=a[3];
    sm[tid*NE+4]=b[0]; sm[tid*NE+5]=b[1]; sm[tid*NE+6]=b[2]; sm[tid*NE+7]=b[3];
    __syncthreads();
    for (int s = 128; s > 0; s >>= 1) {
        if (tid < s) {
            #pragma unroll
            for (int e2 = 0; e2 < NE; ++e2)
                sm[tid * NE + e2] += sm[(tid + s) * NE + e2];
        }
        __syncthreads();
    }
    if (tid < NE) partial[blockIdx.x * NE + tid] = sm[tid];
}

__global__ __launch_bounds__(64) void aux2_kernel(
    const float* __restrict__ partial, float* __restrict__ outAux)
{
    __shared__ float sm[NE];
    int tid = threadIdx.x;
    if (tid < NE) {
        float s = 0.f;
        for (int b = 0; b < 32; ++b) s += partial[b * NE + tid];
        sm[tid] = s;
    }
    __syncthreads();
    if (tid == 0) {
        float ssum = 0.f;
        #pragma unroll
        for (int e2 = 0; e2 < NE; ++e2) {
            float v = sm[e2] * (1.f / (float)TOK);
            ssum += v * v;
        }
        outAux[0] = (float)NE * ssum;
    }
}

extern "C" void kernel_launch(void* const* d_in, const int* in_sizes, int n_in,
                              void* d_out, int out_size, void* d_ws, size_t ws_size,
                              hipStream_t stream) {
    const float* x  = (const float*)d_in[0];
    const float* W1 = (const float*)d_in[1];
    const float* b1 = (const float*)d_in[2];
    const float* W2 = (const float*)d_in[3];
    const float* b2 = (const float*)d_in[4];
    const float* Wr = (const float*)d_in[5];
    const float* br = (const float*)d_in[6];
    float* out = (float*)d_out;
    char* ws = (char*)d_ws;

    int*   cnt   = (int*)(ws + WS_CNT);
    float* rw    = (float*)(ws + WS_RW);
    int*   lists = (int*)(ws + WS_LST);
    float* probs = (float*)(ws + WS_PRB);
    float* part  = (float*)(ws + WS_PART);
    unsigned short* xb   = (unsigned short*)(ws + WS_XB);
    unsigned short* w1t  = (unsigned short*)(ws + WS_W1T);
    unsigned short* w2t  = (unsigned short*)(ws + WS_W2T);
    unsigned short* hbuf = (unsigned short*)(ws + WS_H);
    unsigned short* ybuf = (unsigned short*)(ws + WS_Y);

    hipMemsetAsync(ws, 0, 64, stream);  // zero cnt
    router_kernel<<<TOK / 4, 256, 0, stream>>>(x, Wr, br, cnt, lists, rw, probs);
    cvt_x_kernel<<<(TOK * HD / 8) / 256, 256, 0, stream>>>(x, xb);
    transpose_cvt_kernel<<<dim3(FD / 64, HD / 64, NE), 256, 0, stream>>>(W1, w1t, HD, FD);
    transpose_cvt_kernel<<<dim3(HD / 64, FD / 64, NE), 256, 0, stream>>>(W2, w2t, FD, HD);
    gemm1_kernel<<<dim3(FD / 256, TOK / 256, NE), 512, 0, stream>>>(xb, w1t, b1, cnt, lists, hbuf);
    gemm2_kernel<<<dim3(HD / 256, TOK / 256, NE), 512, 0, stream>>>(hbuf, w2t, b2, cnt, lists, ybuf);
    gather_kernel<<<(TOK * HD / 8) / 256, 256, 0, stream>>>(ybuf, rw, out);
    aux1_kernel<<<32, 256, 0, stream>>>(probs, part);
    aux2_kernel<<<1, 64, 0, stream>>>(part, out + (size_t)TOK * HD);
}

// Round 3
// 821.364 us; speedup vs baseline: 2.3026x; 2.3026x over previous
//
#include <hip/hip_runtime.h>
#include <hip/hip_bf16.h>
#include <stdint.h>

// Problem constants
#define TOK 8192   // B*S
#define HD  1024   // H
#define FD  4096   // F
#define NE  8      // experts
#define BK  32     // K-step (4-deep pipelined)

// Workspace layout (bytes). Total ~278 MB.
#define WS_CNT 0
#define WS_RW  1024
#define WS_LST 131072
#define WS_PRB 524288
#define WS_PART 786432
#define WS_XB  ((size_t)1  << 20)   // xb: 8192*1024*2   = 16 MiB
#define WS_W1T ((size_t)18 << 20)   // W1T: 8*4096*1024*2 = 64 MiB
#define WS_W2T ((size_t)84 << 20)   // W2T: 8*1024*4096*2 = 64 MiB
#define WS_H   ((size_t)150 << 20)  // hbuf: 16384*4096*2 = 128 MiB
#define WS_Y   WS_W1T               // ybuf overlays W1T (dead after gemm1)

typedef __attribute__((ext_vector_type(4))) float  f32x4;
typedef __attribute__((ext_vector_type(8))) short  s16x8;
typedef __attribute__((ext_vector_type(4))) short  s16x4;
typedef __attribute__((ext_vector_type(8))) __bf16 bf16x8;

__device__ inline unsigned short f2bf(float f) {
    __hip_bfloat16 h = __float2bfloat16(f);   // RNE
    return __builtin_bit_cast(unsigned short, h);
}
__device__ inline float bf2f(unsigned short s) {
    unsigned u = ((unsigned)s) << 16;
    return __builtin_bit_cast(float, u);
}
__device__ inline f32x4 mfma_bf16(s16x8 a, s16x8 b, f32x4 c) {
    return __builtin_amdgcn_mfma_f32_16x16x32_bf16(
        __builtin_bit_cast(bf16x8, a), __builtin_bit_cast(bf16x8, b), c, 0, 0, 0);
}
// async global->LDS, 16B per lane. LDS dest wave-uniform base (+lane*16 implicit).
__device__ inline void gl2lds16(const void* g, void* l) {
    __builtin_amdgcn_global_load_lds(
        (const __attribute__((address_space(1))) unsigned int*)g,
        (__attribute__((address_space(3))) unsigned int*)l, 16, 0, 0);
}

// ---------------- Prep: x fp32 -> bf16 ----------------
__global__ __launch_bounds__(256) void cvt_x_kernel(
    const float* __restrict__ x, unsigned short* __restrict__ xb)
{
    size_t g = ((size_t)blockIdx.x * 256 + threadIdx.x) * 8;
    f32x4 a = *(const f32x4*)&x[g];
    f32x4 b = *(const f32x4*)&x[g + 4];
    s16x8 v;
    v[0]=(short)f2bf(a[0]); v[1]=(short)f2bf(a[1]); v[2]=(short)f2bf(a[2]); v[3]=(short)f2bf(a[3]);
    v[4]=(short)f2bf(b[0]); v[5]=(short)f2bf(b[1]); v[6]=(short)f2bf(b[2]); v[7]=(short)f2bf(b[3]);
    *(s16x8*)&xb[g] = v;
}

// ---------------- Prep: transpose + cvt.  src [P][R][C] fp32 -> dst [P][C][R] bf16
__global__ __launch_bounds__(256) void transpose_cvt_kernel(
    const float* __restrict__ src, unsigned short* __restrict__ dst, int R, int C)
{
    __shared__ unsigned short tile[64][65];
    int p  = blockIdx.z;
    int r0 = blockIdx.y * 64, c0 = blockIdx.x * 64;
    const float* s = src + ((size_t)p * R + r0) * C + c0;
    int tc = threadIdx.x & 63, tr = threadIdx.x >> 6;
    #pragma unroll
    for (int i = 0; i < 16; ++i) {
        int r = i * 4 + tr;
        tile[r][tc] = f2bf(s[(size_t)r * C + tc]);
    }
    __syncthreads();
    unsigned short* d = dst + ((size_t)p * C + c0) * R + r0;
    int hq = (threadIdx.x & 15) * 4;
    int fb = threadIdx.x >> 4;
    #pragma unroll
    for (int i = 0; i < 4; ++i) {
        int c = i * 16 + fb;
        s16x4 v;
        v[0] = (short)tile[hq + 0][c]; v[1] = (short)tile[hq + 1][c];
        v[2] = (short)tile[hq + 2][c]; v[3] = (short)tile[hq + 3][c];
        *(s16x4*)&d[(size_t)c * R + hq] = v;
    }
}

// ---------------- Router: 1 wave per token ----------------
__global__ __launch_bounds__(256) void router_kernel(
    const float* __restrict__ x, const float* __restrict__ Wr,
    const float* __restrict__ br, int* __restrict__ cnt,
    int* __restrict__ lists, float* __restrict__ rw,
    float* __restrict__ probs)
{
    int gid  = blockIdx.x * 256 + threadIdx.x;
    int tok  = gid >> 6;
    int lane = threadIdx.x & 63;
    const float* xr = x + (size_t)tok * HD;
    float acc[NE] = {0.f,0.f,0.f,0.f,0.f,0.f,0.f,0.f};
    #pragma unroll 4
    for (int i = 0; i < HD / 64; ++i) {
        float xv = xr[i * 64 + lane];
        const f32x4* w = (const f32x4*)(Wr + (size_t)(i * 64 + lane) * NE);
        f32x4 w0 = w[0], w1 = w[1];
        acc[0] += xv * w0[0]; acc[1] += xv * w0[1];
        acc[2] += xv * w0[2]; acc[3] += xv * w0[3];
        acc[4] += xv * w1[0]; acc[5] += xv * w1[1];
        acc[6] += xv * w1[2]; acc[7] += xv * w1[3];
    }
    #pragma unroll
    for (int e = 0; e < NE; ++e) {
        float v = acc[e];
        #pragma unroll
        for (int off = 32; off > 0; off >>= 1) v += __shfl_down(v, off);
        acc[e] = v;
    }
    if (lane == 0) {
        float lg[NE];
        #pragma unroll
        for (int e = 0; e < NE; ++e) lg[e] = acc[e] + br[e];
        float m = lg[0];
        #pragma unroll
        for (int e = 1; e < NE; ++e) m = fmaxf(m, lg[e]);
        float s = 0.f, p[NE];
        #pragma unroll
        for (int e = 0; e < NE; ++e) { p[e] = __expf(lg[e] - m); s += p[e]; }
        float inv = 1.f / s;
        f32x4 p0 = {p[0]*inv, p[1]*inv, p[2]*inv, p[3]*inv};
        f32x4 p1 = {p[4]*inv, p[5]*inv, p[6]*inv, p[7]*inv};
        *(f32x4*)&probs[(size_t)tok * NE]     = p0;
        *(f32x4*)&probs[(size_t)tok * NE + 4] = p1;
        int e0 = 0;
        #pragma unroll
        for (int e = 1; e < NE; ++e) if (lg[e] > lg[e0]) e0 = e;
        int e1 = (e0 == 0) ? 1 : 0;
        #pragma unroll
        for (int e = 0; e < NE; ++e) if (e != e0 && lg[e] > lg[e1]) e1 = e;
        float t1 = __expf(lg[e1] - lg[e0]);
        float w0 = 1.f / (1.f + t1);
        rw[tok * 2 + 0] = w0;
        rw[tok * 2 + 1] = t1 * w0;
        int p0i = atomicAdd(&cnt[e0], 1);
        lists[e0 * TOK + p0i] = (tok << 1);
        int p1i = atomicAdd(&cnt[e1], 1);
        lists[e1 * TOK + p1i] = (tok << 1) | 1;
    }
}

// ============ GEMM main-loop machinery (128x128 tile, 4 waves, BK=32, 4-deep) ============
// Round-0's verified coarse schedule, shrunk from 256^2/8-wave (1 block/CU, barrier convoy)
// to 128^2/4-wave: LDS = 4 buffers x (A 8KiB + B 8KiB) = 64 KiB -> 2 blocks/CU.
// Inter-block overlap (m114) hides the per-K-step stage-wait that convoyed round-0.
// Chunk c' within row XOR-swizzled by ((row>>1)&3): 2-way bank aliasing (free) on
// both the ds_read_b128 side and (pre-applied) the global source side.

#define GEMM_STAGE(kt3)                                                        \
    {                                                                          \
        int b3 = (kt3) & 3;                                                    \
        gl2lds16(ga[0] + (size_t)(kt3) * BK, &As[b3][(w * 64) * 8]);           \
        gl2lds16(ga[1] + (size_t)(kt3) * BK, &As[b3][(256 + w * 64) * 8]);     \
        gl2lds16(gb[0] + (size_t)(kt3) * BK, &Bs[b3][(w * 64) * 8]);           \
        gl2lds16(gb[1] + (size_t)(kt3) * BK, &Bs[b3][(256 + w * 64) * 8]);     \
    }

#define GEMM_COMPUTE(kt)                                                       \
    {                                                                          \
        int b = (kt) & 3;                                                      \
        s16x8 af[4], bfr[4];                                                   \
        _Pragma("unroll")                                                      \
        for (int mi = 0; mi < 4; ++mi) {                                       \
            int r = wr * 64 + mi * 16 + rl;                                    \
            af[mi] = *(const s16x8*)&As[b][r * 32 + ((q ^ ((r >> 1) & 3)) << 3)]; \
        }                                                                      \
        _Pragma("unroll")                                                      \
        for (int ni = 0; ni < 4; ++ni) {                                       \
            int n = wc * 64 + ni * 16 + rl;                                    \
            bfr[ni] = *(const s16x8*)&Bs[b][n * 32 + ((q ^ ((n >> 1) & 3)) << 3)]; \
        }                                                                      \
        __builtin_amdgcn_s_setprio(1);                                         \
        _Pragma("unroll")                                                      \
        for (int mi = 0; mi < 4; ++mi)                                         \
            _Pragma("unroll")                                                  \
            for (int ni = 0; ni < 4; ++ni)                                     \
                acc[mi][ni] = mfma_bf16(af[mi], bfr[ni], acc[mi][ni]);         \
        __builtin_amdgcn_s_setprio(0);                                         \
    }

// main loop: counted vmcnt — per-wave 4 loads/stage, 2 stages allowed in flight
#define GEMM_MAINLOOP(NT)                                                      \
    GEMM_STAGE(0); GEMM_STAGE(1); GEMM_STAGE(2);                               \
    for (int kt = 0; kt < (NT); ++kt) {                                        \
        if (kt + 2 < (NT))      asm volatile("s_waitcnt vmcnt(8)" ::: "memory"); \
        else if (kt + 1 < (NT)) asm volatile("s_waitcnt vmcnt(4)" ::: "memory"); \
        else                    asm volatile("s_waitcnt vmcnt(0)" ::: "memory"); \
        __builtin_amdgcn_s_barrier();                                          \
        GEMM_COMPUTE(kt);                                                      \
        if (kt + 3 < (NT)) GEMM_STAGE(kt + 3);                                 \
    }

// ---------------- GEMM1: hbuf[base+row] = gelu(xb[tok(row)] @ W1T[e]^T + b1[e]) ----------------
__global__ __launch_bounds__(256, 2) void gemm1_kernel(
    const unsigned short* __restrict__ xb, const unsigned short* __restrict__ w1t,
    const float* __restrict__ b1, const int* __restrict__ cnt,
    const int* __restrict__ lists, unsigned short* __restrict__ hbuf)
{
    int e = blockIdx.z;
    int nc = cnt[e];
    int row0 = blockIdx.y * 128;
    if (row0 >= nc) return;
    int base = 0;
    for (int i = 0; i < e; ++i) base += cnt[i];
    int cb = blockIdx.x * 128;

    __shared__ unsigned short As[4][128 * BK];
    __shared__ unsigned short Bs[4][128 * BK];

    int tid  = threadIdx.x;
    int lane = tid & 63;
    int w    = tid >> 6;     // 0..3
    int wr   = w >> 1;       // M half (0..1)
    int wc   = w & 1;        // N half (0..1)
    int rl   = lane & 15;
    int q    = lane >> 4;    // k-chunk 0..3

    // per-stage global pointers: thread covers chunks tid and 256+tid of each 128x32 tile
    const unsigned short* ga[2];
    const unsigned short* gb[2];
    #pragma unroll
    for (int i = 0; i < 2; ++i) {
        int ch  = i * 256 + tid;
        int row = ch >> 2;
        int kc  = (ch & 3) ^ ((row >> 1) & 3);
        int lr  = row0 + row;
        int tok = (lr < nc) ? (lists[e * TOK + lr] >> 1) : 0;
        ga[i] = xb + (size_t)tok * HD + kc * 8;
        gb[i] = w1t + ((size_t)e * FD + cb + row) * HD + kc * 8;
    }

    f32x4 acc[4][4];
    #pragma unroll
    for (int i = 0; i < 4; ++i)
        #pragma unroll
        for (int j = 0; j < 4; ++j) acc[i][j] = (f32x4){0.f, 0.f, 0.f, 0.f};

    GEMM_MAINLOOP(HD / BK)   // 32 iters

    // epilogue: + b1, exact GELU, bf16 store, expert-packed rows
    int col0 = cb + wc * 64 + rl;
    float b1v[4];
    #pragma unroll
    for (int ni = 0; ni < 4; ++ni) b1v[ni] = b1[e * FD + col0 + ni * 16];
    #pragma unroll
    for (int mi = 0; mi < 4; ++mi) {
        #pragma unroll
        for (int j = 0; j < 4; ++j) {
            int grow = row0 + wr * 64 + mi * 16 + q * 4 + j;
            if (grow < nc) {
                unsigned short* dst = hbuf + (size_t)(base + grow) * FD + col0;
                #pragma unroll
                for (int ni = 0; ni < 4; ++ni) {
                    float v = acc[mi][ni][j] + b1v[ni];
                    v = 0.5f * v * (1.f + erff(v * 0.70710678118654752f));
                    dst[ni * 16] = f2bf(v);
                }
            }
        }
    }
}

// ---------------- GEMM2: y = hbuf[base+row] @ W2T[e]^T + b2[e], scatter to ybuf ----------------
__global__ __launch_bounds__(256, 2) void gemm2_kernel(
    const unsigned short* __restrict__ hbuf, const unsigned short* __restrict__ w2t,
    const float* __restrict__ b2, const int* __restrict__ cnt,
    const int* __restrict__ lists, unsigned short* __restrict__ ybuf)
{
    int e = blockIdx.z;
    int nc = cnt[e];
    int row0 = blockIdx.y * 128;
    if (row0 >= nc) return;
    int base = 0;
    for (int i = 0; i < e; ++i) base += cnt[i];
    int cb = blockIdx.x * 128;

    __shared__ unsigned short As[4][128 * BK];
    __shared__ unsigned short Bs[4][128 * BK];

    int tid  = threadIdx.x;
    int lane = tid & 63;
    int w    = tid >> 6;
    int wr   = w >> 1;
    int wc   = w & 1;
    int rl   = lane & 15;
    int q    = lane >> 4;

    const unsigned short* ga[2];
    const unsigned short* gb[2];
    #pragma unroll
    for (int i = 0; i < 2; ++i) {
        int ch  = i * 256 + tid;
        int row = ch >> 2;
        int kc  = (ch & 3) ^ ((row >> 1) & 3);
        int lr  = row0 + row;
        int hrow = base + ((lr < nc) ? lr : (nc - 1));
        ga[i] = hbuf + (size_t)hrow * FD + kc * 8;
        gb[i] = w2t + ((size_t)e * HD + cb + row) * FD + kc * 8;
    }

    f32x4 acc[4][4];
    #pragma unroll
    for (int i = 0; i < 4; ++i)
        #pragma unroll
        for (int j = 0; j < 4; ++j) acc[i][j] = (f32x4){0.f, 0.f, 0.f, 0.f};

    GEMM_MAINLOOP(FD / BK)   // 128 iters

    int col0 = cb + wc * 64 + rl;
    float b2v[4];
    #pragma unroll
    for (int ni = 0; ni < 4; ++ni) b2v[ni] = b2[e * HD + col0 + ni * 16];
    #pragma unroll
    for (int mi = 0; mi < 4; ++mi) {
        #pragma unroll
        for (int j = 0; j < 4; ++j) {
            int grow = row0 + wr * 64 + mi * 16 + q * 4 + j;
            if (grow < nc) {
                int entry = lists[e * TOK + grow];
                unsigned short* dst = ybuf + ((size_t)((entry & 1) * TOK + (entry >> 1))) * HD + col0;
                #pragma unroll
                for (int ni = 0; ni < 4; ++ni)
                    dst[ni * 16] = f2bf(acc[mi][ni][j] + b2v[ni]);
            }
        }
    }
}

// ---------------- Gather: out = w0*y[k=0] + w1*y[k=1] ----------------
__global__ __launch_bounds__(256) void gather_kernel(
    const unsigned short* __restrict__ ybuf, const float* __restrict__ rw,
    float* __restrict__ out)
{
    int g = blockIdx.x * 256 + threadIdx.x;
    int t = g >> 7;
    int h0 = (g & 127) * 8;
    float w0 = rw[t * 2 + 0];
    float w1 = rw[t * 2 + 1];
    s16x8 y0 = *(const s16x8*)&ybuf[(size_t)t * HD + h0];
    s16x8 y1 = *(const s16x8*)&ybuf[((size_t)TOK + t) * HD + h0];
    f32x4 o0, o1;
    #pragma unroll
    for (int j = 0; j < 4; ++j) {
        o0[j] = w0 * bf2f((unsigned short)y0[j])   + w1 * bf2f((unsigned short)y1[j]);
        o1[j] = w0 * bf2f((unsigned short)y0[j+4]) + w1 * bf2f((unsigned short)y1[j+4]);
    }
    *(f32x4*)&out[(size_t)t * HD + h0]     = o0;
    *(f32x4*)&out[(size_t)t * HD + h0 + 4] = o1;
}

// ---------------- Aux loss: 32-block partial + final reduce ----------------
__global__ __launch_bounds__(256) void aux1_kernel(
    const float* __restrict__ probs, float* __restrict__ partial)
{
    __shared__ float sm[256 * NE];
    int tid = threadIdx.x;
    int t = blockIdx.x * 256 + tid;
    const f32x4* p = (const f32x4*)&probs[(size_t)t * NE];
    f32x4 a = p[0], b = p[1];
    sm[tid*NE+0]=a[0]; sm[tid*NE+1]=a[1]; sm[tid*NE+2]=a[2]; sm[tid*NE+3]=a[3];
    sm[tid*NE+4]=b[0]; sm[tid*NE+5]=b[1]; sm[tid*NE+6]=b[2]; sm[tid*NE+7]=b[3];
    __syncthreads();
    for (int s = 128; s > 0; s >>= 1) {
        if (tid < s) {
            #pragma unroll
            for (int e2 = 0; e2 < NE; ++e2)
                sm[tid * NE + e2] += sm[(tid + s) * NE + e2];
        }
        __syncthreads();
    }
    if (tid < NE) partial[blockIdx.x * NE + tid] = sm[tid];
}

__global__ __launch_bounds__(64) void aux2_kernel(
    const float* __restrict__ partial, float* __restrict__ outAux)
{
    __shared__ float sm[NE];
    int tid = threadIdx.x;
    if (tid < NE) {
        float s = 0.f;
        for (int b = 0; b < 32; ++b) s += partial[b * NE + tid];
        sm[tid] = s;
    }
    __syncthreads();
    if (tid == 0) {
        float ssum = 0.f;
        #pragma unroll
        for (int e2 = 0; e2 < NE; ++e2) {
            float v = sm[e2] * (1.f / (float)TOK);
            ssum += v * v;
        }
        outAux[0] = (float)NE * ssum;
    }
}

extern "C" void kernel_launch(void* const* d_in, const int* in_sizes, int n_in,
                              void* d_out, int out_size, void* d_ws, size_t ws_size,
                              hipStream_t stream) {
    const float* x  = (const float*)d_in[0];
    const float* W1 = (const float*)d_in[1];
    const float* b1 = (const float*)d_in[2];
    const float* W2 = (const float*)d_in[3];
    const float* b2 = (const float*)d_in[4];
    const float* Wr = (const float*)d_in[5];
    const float* br = (const float*)d_in[6];
    float* out = (float*)d_out;
    char* ws = (char*)d_ws;

    int*   cnt   = (int*)(ws + WS_CNT);
    float* rw    = (float*)(ws + WS_RW);
    int*   lists = (int*)(ws + WS_LST);
    float* probs = (float*)(ws + WS_PRB);
    float* part  = (float*)(ws + WS_PART);
    unsigned short* xb   = (unsigned short*)(ws + WS_XB);
    unsigned short* w1t  = (unsigned short*)(ws + WS_W1T);
    unsigned short* w2t  = (unsigned short*)(ws + WS_W2T);
    unsigned short* hbuf = (unsigned short*)(ws + WS_H);
    unsigned short* ybuf = (unsigned short*)(ws + WS_Y);

    hipMemsetAsync(ws, 0, 64, stream);  // zero cnt
    router_kernel<<<TOK / 4, 256, 0, stream>>>(x, Wr, br, cnt, lists, rw, probs);
    cvt_x_kernel<<<(TOK * HD / 8) / 256, 256, 0, stream>>>(x, xb);
    transpose_cvt_kernel<<<dim3(FD / 64, HD / 64, NE), 256, 0, stream>>>(W1, w1t, HD, FD);
    transpose_cvt_kernel<<<dim3(HD / 64, FD / 64, NE), 256, 0, stream>>>(W2, w2t, FD, HD);
    gemm1_kernel<<<dim3(FD / 128, TOK / 128, NE), 256, 0, stream>>>(xb, w1t, b1, cnt, lists, hbuf);
    gemm2_kernel<<<dim3(HD / 128, TOK / 128, NE), 256, 0, stream>>>(hbuf, w2t, b2, cnt, lists, ybuf);
    gather_kernel<<<(TOK * HD / 8) / 256, 256, 0, stream>>>(ybuf, rw, out);
    aux1_kernel<<<32, 256, 0, stream>>>(probs, part);
    aux2_kernel<<<1, 64, 0, stream>>>(part, out + (size_t)TOK * HD);
}

// Round 4
// 744.155 us; speedup vs baseline: 2.5415x; 1.1038x over previous
//
#include <hip/hip_runtime.h>
#include <hip/hip_bf16.h>
#include <stdint.h>

// Problem constants
#define TOK 8192   // B*S
#define HD  1024   // H
#define FD  4096   // F
#define NE  8      // experts
#define BK  32     // K-step

// Workspace layout (bytes). Total ~278 MB.
#define WS_CNT 0
#define WS_RW  1024
#define WS_LST 131072
#define WS_PRB 524288
#define WS_PART 786432
#define WS_XB  ((size_t)1  << 20)   // xb: 8192*1024*2   = 16 MiB
#define WS_W1T ((size_t)18 << 20)   // W1T: 8*4096*1024*2 = 64 MiB
#define WS_W2T ((size_t)84 << 20)   // W2T: 8*1024*4096*2 = 64 MiB
#define WS_H   ((size_t)150 << 20)  // hbuf: 16384*4096*2 = 128 MiB
#define WS_Y   WS_W1T               // ybuf overlays W1T (dead after gemm1)

typedef __attribute__((ext_vector_type(4))) float  f32x4;
typedef __attribute__((ext_vector_type(8))) short  s16x8;
typedef __attribute__((ext_vector_type(4))) short  s16x4;
typedef __attribute__((ext_vector_type(8))) __bf16 bf16x8;

__device__ inline unsigned short f2bf(float f) {
    __hip_bfloat16 h = __float2bfloat16(f);   // RNE
    return __builtin_bit_cast(unsigned short, h);
}
__device__ inline float bf2f(unsigned short s) {
    unsigned u = ((unsigned)s) << 16;
    return __builtin_bit_cast(float, u);
}
__device__ inline f32x4 mfma_bf16(s16x8 a, s16x8 b, f32x4 c) {
    return __builtin_amdgcn_mfma_f32_16x16x32_bf16(
        __builtin_bit_cast(bf16x8, a), __builtin_bit_cast(bf16x8, b), c, 0, 0, 0);
}
// async global->LDS, 16B per lane. LDS dest wave-uniform base (+lane*16 implicit).
__device__ inline void gl2lds16(const void* g, void* l) {
    __builtin_amdgcn_global_load_lds(
        (const __attribute__((address_space(1))) unsigned int*)g,
        (__attribute__((address_space(3))) unsigned int*)l, 16, 0, 0);
}

// ---------------- Prep: transpose + cvt.  src [P][R][C] fp32 -> dst [P][C][R] bf16
__global__ __launch_bounds__(256) void transpose_cvt_kernel(
    const float* __restrict__ src, unsigned short* __restrict__ dst, int R, int C)
{
    __shared__ unsigned short tile[64][65];
    int p  = blockIdx.z;
    int r0 = blockIdx.y * 64, c0 = blockIdx.x * 64;
    const float* s = src + ((size_t)p * R + r0) * C + c0;
    int tc = threadIdx.x & 63, tr = threadIdx.x >> 6;
    #pragma unroll
    for (int i = 0; i < 16; ++i) {
        int r = i * 4 + tr;
        tile[r][tc] = f2bf(s[(size_t)r * C + tc]);
    }
    __syncthreads();
    unsigned short* d = dst + ((size_t)p * C + c0) * R + r0;
    int hq = (threadIdx.x & 15) * 4;
    int fb = threadIdx.x >> 4;
    #pragma unroll
    for (int i = 0; i < 4; ++i) {
        int c = i * 16 + fb;
        s16x4 v;
        v[0] = (short)tile[hq + 0][c]; v[1] = (short)tile[hq + 1][c];
        v[2] = (short)tile[hq + 2][c]; v[3] = (short)tile[hq + 3][c];
        *(s16x4*)&d[(size_t)c * R + hq] = v;
    }
}

// ---------------- Router: 1 wave per token (also emits xb = bf16(x)) ----------------
__global__ __launch_bounds__(256) void router_kernel(
    const float* __restrict__ x, const float* __restrict__ Wr,
    const float* __restrict__ br, int* __restrict__ cnt,
    int* __restrict__ lists, float* __restrict__ rw,
    float* __restrict__ probs, unsigned short* __restrict__ xb)
{
    int gid  = blockIdx.x * 256 + threadIdx.x;
    int tok  = gid >> 6;
    int lane = threadIdx.x & 63;
    const float* xr = x + (size_t)tok * HD;
    unsigned short* xbr = xb + (size_t)tok * HD;
    float acc[NE] = {0.f,0.f,0.f,0.f,0.f,0.f,0.f,0.f};
    #pragma unroll 4
    for (int i = 0; i < HD / 64; ++i) {
        float xv = xr[i * 64 + lane];
        xbr[i * 64 + lane] = f2bf(xv);          // fused x -> bf16 conversion
        const f32x4* w = (const f32x4*)(Wr + (size_t)(i * 64 + lane) * NE);
        f32x4 w0 = w[0], w1 = w[1];
        acc[0] += xv * w0[0]; acc[1] += xv * w0[1];
        acc[2] += xv * w0[2]; acc[3] += xv * w0[3];
        acc[4] += xv * w1[0]; acc[5] += xv * w1[1];
        acc[6] += xv * w1[2]; acc[7] += xv * w1[3];
    }
    #pragma unroll
    for (int e = 0; e < NE; ++e) {
        float v = acc[e];
        #pragma unroll
        for (int off = 32; off > 0; off >>= 1) v += __shfl_down(v, off);
        acc[e] = v;
    }
    if (lane == 0) {
        float lg[NE];
        #pragma unroll
        for (int e = 0; e < NE; ++e) lg[e] = acc[e] + br[e];
        float m = lg[0];
        #pragma unroll
        for (int e = 1; e < NE; ++e) m = fmaxf(m, lg[e]);
        float s = 0.f, p[NE];
        #pragma unroll
        for (int e = 0; e < NE; ++e) { p[e] = __expf(lg[e] - m); s += p[e]; }
        float inv = 1.f / s;
        f32x4 p0 = {p[0]*inv, p[1]*inv, p[2]*inv, p[3]*inv};
        f32x4 p1 = {p[4]*inv, p[5]*inv, p[6]*inv, p[7]*inv};
        *(f32x4*)&probs[(size_t)tok * NE]     = p0;
        *(f32x4*)&probs[(size_t)tok * NE + 4] = p1;
        int e0 = 0;
        #pragma unroll
        for (int e = 1; e < NE; ++e) if (lg[e] > lg[e0]) e0 = e;
        int e1 = (e0 == 0) ? 1 : 0;
        #pragma unroll
        for (int e = 0; e < NE; ++e) if (e != e0 && lg[e] > lg[e1]) e1 = e;
        float t1 = __expf(lg[e1] - lg[e0]);
        float w0 = 1.f / (1.f + t1);
        rw[tok * 2 + 0] = w0;
        rw[tok * 2 + 1] = t1 * w0;
        int p0i = atomicAdd(&cnt[e0], 1);
        lists[e0 * TOK + p0i] = (tok << 1);
        int p1i = atomicAdd(&cnt[e1], 1);
        lists[e1 * TOK + p1i] = (tok << 1) | 1;
    }
}

// ============ GEMM main-loop machinery (128x128 tile, 4 waves, BK=32, 3-buffer) ============
// m97-class structure at 3 blocks/CU: LDS = 3 bufs x (A 8KiB + B 8KiB) = 48 KiB.
// 12 resident waves/CU supply the inter-block overlap (m114) that hides the per-K-step
// stage-wait; counted vmcnt keeps 1 stage in flight across the barrier (never drains to 0
// in steady state).
// Chunk c' within row XOR-swizzled by ((row>>1)&3): 2-way bank aliasing (free) on
// both the ds_read_b128 side and (pre-applied) the global source side.
//
// Per-iter schedule: vmcnt(4) [drain stage kt; stage kt+1 stays in flight] -> barrier ->
// issue stage kt+2 (buf (kt+2)%3 = buf(kt-1), readers done before this barrier) ->
// compute kt. Tail: vmcnt(0) on last iter only.

#define GEMM_STAGE(kt3, b3)                                                    \
    {                                                                          \
        gl2lds16(ga[0] + (size_t)(kt3) * BK, &As[b3][(w * 64) * 8]);           \
        gl2lds16(ga[1] + (size_t)(kt3) * BK, &As[b3][(256 + w * 64) * 8]);     \
        gl2lds16(gb[0] + (size_t)(kt3) * BK, &Bs[b3][(w * 64) * 8]);           \
        gl2lds16(gb[1] + (size_t)(kt3) * BK, &Bs[b3][(256 + w * 64) * 8]);     \
    }

#define GEMM_COMPUTE(b)                                                        \
    {                                                                          \
        s16x8 af[4], bfr[4];                                                   \
        _Pragma("unroll")                                                      \
        for (int mi = 0; mi < 4; ++mi) {                                       \
            int r = wr * 64 + mi * 16 + rl;                                    \
            af[mi] = *(const s16x8*)&As[b][r * 32 + ((q ^ ((r >> 1) & 3)) << 3)]; \
        }                                                                      \
        _Pragma("unroll")                                                      \
        for (int ni = 0; ni < 4; ++ni) {                                       \
            int n = wc * 64 + ni * 16 + rl;                                    \
            bfr[ni] = *(const s16x8*)&Bs[b][n * 32 + ((q ^ ((n >> 1) & 3)) << 3)]; \
        }                                                                      \
        __builtin_amdgcn_s_setprio(1);                                         \
        _Pragma("unroll")                                                      \
        for (int mi = 0; mi < 4; ++mi)                                         \
            _Pragma("unroll")                                                  \
            for (int ni = 0; ni < 4; ++ni)                                     \
                acc[mi][ni] = mfma_bf16(af[mi], bfr[ni], acc[mi][ni]);         \
        __builtin_amdgcn_s_setprio(0);                                         \
    }

#define GEMM_MAINLOOP(NT)                                                      \
    GEMM_STAGE(0, 0); GEMM_STAGE(1, 1);                                        \
    int bc = 0;                                                                \
    for (int kt = 0; kt < (NT); ++kt) {                                        \
        if (kt + 1 < (NT)) asm volatile("s_waitcnt vmcnt(4)" ::: "memory");    \
        else               asm volatile("s_waitcnt vmcnt(0)" ::: "memory");    \
        __builtin_amdgcn_s_barrier();                                          \
        if (kt + 2 < (NT)) {                                                   \
            int b2 = bc + 2; if (b2 >= 3) b2 -= 3;                             \
            GEMM_STAGE(kt + 2, b2);                                            \
        }                                                                      \
        GEMM_COMPUTE(bc);                                                      \
        ++bc; if (bc >= 3) bc = 0;                                             \
    }

// ---------------- GEMM1: hbuf[base+row] = gelu(xb[tok(row)] @ W1T[e]^T + b1[e]) ----------------
__global__ __launch_bounds__(256, 3) void gemm1_kernel(
    const unsigned short* __restrict__ xb, const unsigned short* __restrict__ w1t,
    const float* __restrict__ b1, const int* __restrict__ cnt,
    const int* __restrict__ lists, unsigned short* __restrict__ hbuf)
{
    int e = blockIdx.z;
    int nc = cnt[e];
    int row0 = blockIdx.y * 128;
    if (row0 >= nc) return;
    int base = 0;
    for (int i = 0; i < e; ++i) base += cnt[i];
    int cb = blockIdx.x * 128;

    __shared__ unsigned short As[3][128 * BK];
    __shared__ unsigned short Bs[3][128 * BK];

    int tid  = threadIdx.x;
    int lane = tid & 63;
    int w    = tid >> 6;     // 0..3
    int wr   = w >> 1;       // M half (0..1)
    int wc   = w & 1;        // N half (0..1)
    int rl   = lane & 15;
    int q    = lane >> 4;    // k-chunk 0..3

    // per-stage global pointers: thread covers chunks tid and 256+tid of each 128x32 tile
    const unsigned short* ga[2];
    const unsigned short* gb[2];
    #pragma unroll
    for (int i = 0; i < 2; ++i) {
        int ch  = i * 256 + tid;
        int row = ch >> 2;
        int kc  = (ch & 3) ^ ((row >> 1) & 3);
        int lr  = row0 + row;
        int tok = (lr < nc) ? (lists[e * TOK + lr] >> 1) : 0;
        ga[i] = xb + (size_t)tok * HD + kc * 8;
        gb[i] = w1t + ((size_t)e * FD + cb + row) * HD + kc * 8;
    }

    f32x4 acc[4][4];
    #pragma unroll
    for (int i = 0; i < 4; ++i)
        #pragma unroll
        for (int j = 0; j < 4; ++j) acc[i][j] = (f32x4){0.f, 0.f, 0.f, 0.f};

    GEMM_MAINLOOP(HD / BK)   // 32 iters

    // epilogue: + b1, exact GELU, bf16 store, expert-packed rows
    int col0 = cb + wc * 64 + rl;
    float b1v[4];
    #pragma unroll
    for (int ni = 0; ni < 4; ++ni) b1v[ni] = b1[e * FD + col0 + ni * 16];
    #pragma unroll
    for (int mi = 0; mi < 4; ++mi) {
        #pragma unroll
        for (int j = 0; j < 4; ++j) {
            int grow = row0 + wr * 64 + mi * 16 + q * 4 + j;
            if (grow < nc) {
                unsigned short* dst = hbuf + (size_t)(base + grow) * FD + col0;
                #pragma unroll
                for (int ni = 0; ni < 4; ++ni) {
                    float v = acc[mi][ni][j] + b1v[ni];
                    v = 0.5f * v * (1.f + erff(v * 0.70710678118654752f));
                    dst[ni * 16] = f2bf(v);
                }
            }
        }
    }
}

// ---------------- GEMM2: y = hbuf[base+row] @ W2T[e]^T + b2[e], scatter to ybuf ----------------
__global__ __launch_bounds__(256, 3) void gemm2_kernel(
    const unsigned short* __restrict__ hbuf, const unsigned short* __restrict__ w2t,
    const float* __restrict__ b2, const int* __restrict__ cnt,
    const int* __restrict__ lists, unsigned short* __restrict__ ybuf)
{
    int e = blockIdx.z;
    int nc = cnt[e];
    int row0 = blockIdx.y * 128;
    if (row0 >= nc) return;
    int base = 0;
    for (int i = 0; i < e; ++i) base += cnt[i];
    int cb = blockIdx.x * 128;

    __shared__ unsigned short As[3][128 * BK];
    __shared__ unsigned short Bs[3][128 * BK];

    int tid  = threadIdx.x;
    int lane = tid & 63;
    int w    = tid >> 6;
    int wr   = w >> 1;
    int wc   = w & 1;
    int rl   = lane & 15;
    int q    = lane >> 4;

    const unsigned short* ga[2];
    const unsigned short* gb[2];
    #pragma unroll
    for (int i = 0; i < 2; ++i) {
        int ch  = i * 256 + tid;
        int row = ch >> 2;
        int kc  = (ch & 3) ^ ((row >> 1) & 3);
        int lr  = row0 + row;
        int hrow = base + ((lr < nc) ? lr : (nc - 1));
        ga[i] = hbuf + (size_t)hrow * FD + kc * 8;
        gb[i] = w2t + ((size_t)e * HD + cb + row) * FD + kc * 8;
    }

    f32x4 acc[4][4];
    #pragma unroll
    for (int i = 0; i < 4; ++i)
        #pragma unroll
        for (int j = 0; j < 4; ++j) acc[i][j] = (f32x4){0.f, 0.f, 0.f, 0.f};

    GEMM_MAINLOOP(FD / BK)   // 128 iters

    int col0 = cb + wc * 64 + rl;
    float b2v[4];
    #pragma unroll
    for (int ni = 0; ni < 4; ++ni) b2v[ni] = b2[e * HD + col0 + ni * 16];
    #pragma unroll
    for (int mi = 0; mi < 4; ++mi) {
        #pragma unroll
        for (int j = 0; j < 4; ++j) {
            int grow = row0 + wr * 64 + mi * 16 + q * 4 + j;
            if (grow < nc) {
                int entry = lists[e * TOK + grow];
                unsigned short* dst = ybuf + ((size_t)((entry & 1) * TOK + (entry >> 1))) * HD + col0;
                #pragma unroll
                for (int ni = 0; ni < 4; ++ni)
                    dst[ni * 16] = f2bf(acc[mi][ni][j] + b2v[ni]);
            }
        }
    }
}

// ---------------- Gather: out = w0*y[k=0] + w1*y[k=1] ----------------
__global__ __launch_bounds__(256) void gather_kernel(
    const unsigned short* __restrict__ ybuf, const float* __restrict__ rw,
    float* __restrict__ out)
{
    int g = blockIdx.x * 256 + threadIdx.x;
    int t = g >> 7;
    int h0 = (g & 127) * 8;
    float w0 = rw[t * 2 + 0];
    float w1 = rw[t * 2 + 1];
    s16x8 y0 = *(const s16x8*)&ybuf[(size_t)t * HD + h0];
    s16x8 y1 = *(const s16x8*)&ybuf[((size_t)TOK + t) * HD + h0];
    f32x4 o0, o1;
    #pragma unroll
    for (int j = 0; j < 4; ++j) {
        o0[j] = w0 * bf2f((unsigned short)y0[j])   + w1 * bf2f((unsigned short)y1[j]);
        o1[j] = w0 * bf2f((unsigned short)y0[j+4]) + w1 * bf2f((unsigned short)y1[j+4]);
    }
    *(f32x4*)&out[(size_t)t * HD + h0]     = o0;
    *(f32x4*)&out[(size_t)t * HD + h0 + 4] = o1;
}

// ---------------- Aux loss: 32-block partial + final reduce ----------------
__global__ __launch_bounds__(256) void aux1_kernel(
    const float* __restrict__ probs, float* __restrict__ partial)
{
    __shared__ float sm[256 * NE];
    int tid = threadIdx.x;
    int t = blockIdx.x * 256 + tid;
    const f32x4* p = (const f32x4*)&probs[(size_t)t * NE];
    f32x4 a = p[0], b = p[1];
    sm[tid*NE+0]=a[0]; sm[tid*NE+1]=a[1]; sm[tid*NE+2]=a[2]; sm[tid*NE+3]=a[3];
    sm[tid*NE+4]=b[0]; sm[tid*NE+5]=b[1]; sm[tid*NE+6]=b[2]; sm[tid*NE+7]=b[3];
    __syncthreads();
    for (int s = 128; s > 0; s >>= 1) {
        if (tid < s) {
            #pragma unroll
            for (int e2 = 0; e2 < NE; ++e2)
                sm[tid * NE + e2] += sm[(tid + s) * NE + e2];
        }
        __syncthreads();
    }
    if (tid < NE) partial[blockIdx.x * NE + tid] = sm[tid];
}

__global__ __launch_bounds__(64) void aux2_kernel(
    const float* __restrict__ partial, float* __restrict__ outAux)
{
    __shared__ float sm[NE];
    int tid = threadIdx.x;
    if (tid < NE) {
        float s = 0.f;
        for (int b = 0; b < 32; ++b) s += partial[b * NE + tid];
        sm[tid] = s;
    }
    __syncthreads();
    if (tid == 0) {
        float ssum = 0.f;
        #pragma unroll
        for (int e2 = 0; e2 < NE; ++e2) {
            float v = sm[e2] * (1.f / (float)TOK);
            ssum += v * v;
        }
        outAux[0] = (float)NE * ssum;
    }
}

extern "C" void kernel_launch(void* const* d_in, const int* in_sizes, int n_in,
                              void* d_out, int out_size, void* d_ws, size_t ws_size,
                              hipStream_t stream) {
    const float* x  = (const float*)d_in[0];
    const float* W1 = (const float*)d_in[1];
    const float* b1 = (const float*)d_in[2];
    const float* W2 = (const float*)d_in[3];
    const float* b2 = (const float*)d_in[4];
    const float* Wr = (const float*)d_in[5];
    const float* br = (const float*)d_in[6];
    float* out = (float*)d_out;
    char* ws = (char*)d_ws;

    int*   cnt   = (int*)(ws + WS_CNT);
    float* rw    = (float*)(ws + WS_RW);
    int*   lists = (int*)(ws + WS_LST);
    float* probs = (float*)(ws + WS_PRB);
    float* part  = (float*)(ws + WS_PART);
    unsigned short* xb   = (unsigned short*)(ws + WS_XB);
    unsigned short* w1t  = (unsigned short*)(ws + WS_W1T);
    unsigned short* w2t  = (unsigned short*)(ws + WS_W2T);
    unsigned short* hbuf = (unsigned short*)(ws + WS_H);
    unsigned short* ybuf = (unsigned short*)(ws + WS_Y);

    hipMemsetAsync(ws, 0, 64, stream);  // zero cnt
    router_kernel<<<TOK / 4, 256, 0, stream>>>(x, Wr, br, cnt, lists, rw, probs, xb);
    transpose_cvt_kernel<<<dim3(FD / 64, HD / 64, NE), 256, 0, stream>>>(W1, w1t, HD, FD);
    transpose_cvt_kernel<<<dim3(HD / 64, FD / 64, NE), 256, 0, stream>>>(W2, w2t, FD, HD);
    gemm1_kernel<<<dim3(FD / 128, TOK / 128, NE), 256, 0, stream>>>(xb, w1t, b1, cnt, lists, hbuf);
    gemm2_kernel<<<dim3(HD / 128, TOK / 128, NE), 256, 0, stream>>>(hbuf, w2t, b2, cnt, lists, ybuf);
    gather_kernel<<<(TOK * HD / 8) / 256, 256, 0, stream>>>(ybuf, rw, out);
    aux1_kernel<<<32, 256, 0, stream>>>(probs, part);
    aux2_kernel<<<1, 64, 0, stream>>>(part, out + (size_t)TOK * HD);
}